// Round 1
// baseline (1232.332 us; speedup 1.0000x reference)
//
#include <hip/hip_runtime.h>
#include <math.h>

// Problem constants: B=4, S=2048, D=512, H=8, Hd=64
#define SEQ 2048
#define DM 512
#define NH 8
#define HD 64

// ---------------------------------------------------------------------------
// Kernel 1: qkv = x @ Wqkv + bqkv, fused RoPE on q,k, write q/k/v [B,H,S,64]
// 64x64 output tile per block, 256 threads, 4x4 microtile, BK=16.
// ---------------------------------------------------------------------------
__global__ __launch_bounds__(256)
void qkv_gemm_rope(const float* __restrict__ x, const float* __restrict__ W,
                   const float* __restrict__ bias,
                   float* __restrict__ qo, float* __restrict__ ko,
                   float* __restrict__ vo)
{
    __shared__ float As[16][68];   // [k][m], padded stride 68 (16B aligned)
    __shared__ float Bs[16][68];   // [k][n]
    const int tid  = threadIdx.x;
    const int tm   = tid >> 4, tn = tid & 15;
    const int row0 = blockIdx.x * 64;           // token tile
    const int bn   = blockIdx.y;                // 0..23 (24 N-tiles of 64)
    const int col0 = bn * 64;

    const int arow = tid >> 2, ak4 = (tid & 3) << 2;   // A: 64 rows x 16 k
    const int brow = tid >> 4, bc4 = (tid & 15) << 2;  // B: 16 k x 64 n

    float acc[4][4] = {};

    for (int k0 = 0; k0 < DM; k0 += 16) {
        float4 a = *(const float4*)&x[(size_t)(row0 + arow) * DM + k0 + ak4];
        As[ak4 + 0][arow] = a.x;
        As[ak4 + 1][arow] = a.y;
        As[ak4 + 2][arow] = a.z;
        As[ak4 + 3][arow] = a.w;
        *(float4*)&Bs[brow][bc4] =
            *(const float4*)&W[(size_t)(k0 + brow) * (3 * DM) + col0 + bc4];
        __syncthreads();
#pragma unroll
        for (int kk = 0; kk < 16; ++kk) {
            float4 af = *(const float4*)&As[kk][tm << 2];
            float4 bf = *(const float4*)&Bs[kk][tn << 2];
            float av[4] = {af.x, af.y, af.z, af.w};
            float bv[4] = {bf.x, bf.y, bf.z, bf.w};
#pragma unroll
            for (int i = 0; i < 4; ++i)
#pragma unroll
                for (int j = 0; j < 4; ++j)
                    acc[i][j] += av[i] * bv[j];
        }
        __syncthreads();
    }

    const int sel   = bn >> 3;      // 0=q 1=k 2=v
    const int head  = bn & 7;
    const int dbase = tn << 2;      // 0..60 within head dim
    float* dst = (sel == 0) ? qo : ((sel == 1) ? ko : vo);

    const float b0 = bias[col0 + dbase + 0];
    const float b1 = bias[col0 + dbase + 1];
    const float b2 = bias[col0 + dbase + 2];
    const float b3 = bias[col0 + dbase + 3];
    // inv_freq = 10000^(-d/64) = exp(-d * ln(10000)/64), d even
    const float kln  = -0.14391156660393256f;
    const float if0  = expf(kln * (float)(dbase + 0));
    const float if1  = expf(kln * (float)(dbase + 2));

#pragma unroll
    for (int i = 0; i < 4; ++i) {
        int n = row0 + (tm << 2) + i;
        int b = n >> 11, s = n & (SEQ - 1);
        float c0 = acc[i][0] + b0;
        float c1 = acc[i][1] + b1;
        float c2 = acc[i][2] + b2;
        float c3 = acc[i][3] + b3;
        if (sel < 2) {
            float f0 = (float)s * if0;
            float f1 = (float)s * if1;
            float sn0, cs0, sn1, cs1;
            sincosf(f0, &sn0, &cs0);
            sincosf(f1, &sn1, &cs1);
            float r0 = c0 * cs0 - c1 * sn0;
            float r1 = c0 * sn0 + c1 * cs0;
            float r2 = c2 * cs1 - c3 * sn1;
            float r3 = c2 * sn1 + c3 * cs1;
            c0 = r0; c1 = r1; c2 = r2; c3 = r3;
        }
        *(float4*)&dst[(((size_t)(b * NH + head) * SEQ + s) << 6) + dbase] =
            make_float4(c0, c1, c2, c3);
    }
}

// ---------------------------------------------------------------------------
// Kernel 2: flash-style attention. Block = (b,h, 64-row Q tile), 256 threads.
// Online softmax; O accumulator (64x64) in registers, 4x4 per thread.
// Writes attn output in [B, S, H*64] layout so the final GEMM reads row-major.
// ---------------------------------------------------------------------------
__global__ __launch_bounds__(256)
void attn_kernel(const float* __restrict__ q, const float* __restrict__ k,
                 const float* __restrict__ v, float* __restrict__ o)
{
    __shared__ float Qs[64][68];
    __shared__ float Ks[64][68];
    __shared__ float Vs[64][68];
    __shared__ float Ss[64][68];
    __shared__ float mrow[64], lrow[64], arow_s[64];
    __shared__ float red[64][4];

    const int tid = threadIdx.x;
    const int tm  = tid >> 4, tn = tid & 15;
    const int bh  = blockIdx.y;     // 0..31
    const int qt  = blockIdx.x;     // 0..31
    const int b   = bh >> 3, h = bh & 7;

    const float* qb = q + ((size_t)bh * SEQ + qt * 64) * HD;
    const float* kb = k + (size_t)bh * SEQ * HD;
    const float* vb = v + (size_t)bh * SEQ * HD;

    // load Q tile, pre-scaled by 1/sqrt(64)
#pragma unroll
    for (int it = 0; it < 4; ++it) {
        int idx = tid + it * 256;
        int r = idx >> 4, c4 = (idx & 15) << 2;
        float4 qv = *(const float4*)&qb[(r << 6) + c4];
        *(float4*)&Qs[r][c4] = make_float4(qv.x * 0.125f, qv.y * 0.125f,
                                           qv.z * 0.125f, qv.w * 0.125f);
    }
    if (tid < 64) { mrow[tid] = -1e30f; lrow[tid] = 0.f; }

    float oacc[4][4] = {};
    const int srow = tid >> 2, ssub = tid & 3;

    for (int kt = 0; kt < 32; ++kt) {
        __syncthreads();   // previous iter's readers of Ks/Vs/Ss done
        // load K, V tiles
#pragma unroll
        for (int it = 0; it < 4; ++it) {
            int idx = tid + it * 256;
            int r = idx >> 4, c4 = (idx & 15) << 2;
            *(float4*)&Ks[r][c4] = *(const float4*)&kb[((kt * 64 + r) << 6) + c4];
            *(float4*)&Vs[r][c4] = *(const float4*)&vb[((kt * 64 + r) << 6) + c4];
        }
        __syncthreads();

        // S = (Q/8) K^T   (64x64)
        float sacc[4][4] = {};
#pragma unroll
        for (int d0 = 0; d0 < 64; d0 += 4) {
            float4 qa[4], kv[4];
#pragma unroll
            for (int i = 0; i < 4; ++i) qa[i] = *(const float4*)&Qs[(tm << 2) + i][d0];
#pragma unroll
            for (int j = 0; j < 4; ++j) kv[j] = *(const float4*)&Ks[(tn << 2) + j][d0];
#pragma unroll
            for (int i = 0; i < 4; ++i)
#pragma unroll
                for (int j = 0; j < 4; ++j)
                    sacc[i][j] += qa[i].x * kv[j].x + qa[i].y * kv[j].y +
                                  qa[i].z * kv[j].z + qa[i].w * kv[j].w;
        }
#pragma unroll
        for (int i = 0; i < 4; ++i)
            *(float4*)&Ss[(tm << 2) + i][tn << 2] =
                make_float4(sacc[i][0], sacc[i][1], sacc[i][2], sacc[i][3]);
        __syncthreads();

        // online softmax: 4 threads per row
        float mx = -1e30f;
#pragma unroll
        for (int c = 0; c < 16; ++c) mx = fmaxf(mx, Ss[srow][(ssub << 4) + c]);
        red[srow][ssub] = mx;
        __syncthreads();
        if (ssub == 0) {
            float m_old = mrow[srow];
            float m_new = fmaxf(fmaxf(red[srow][0], red[srow][1]),
                                fmaxf(red[srow][2], red[srow][3]));
            m_new = fmaxf(m_old, m_new);
            arow_s[srow] = expf(m_old - m_new);
            mrow[srow] = m_new;
        }
        __syncthreads();
        float m_new = mrow[srow];
        float psum = 0.f;
#pragma unroll
        for (int c = 0; c < 16; ++c) {
            float p = expf(Ss[srow][(ssub << 4) + c] - m_new);
            Ss[srow][(ssub << 4) + c] = p;
            psum += p;
        }
        red[srow][ssub] = psum;
        __syncthreads();
        if (ssub == 0)
            lrow[srow] = lrow[srow] * arow_s[srow] +
                         red[srow][0] + red[srow][1] + red[srow][2] + red[srow][3];
        // rescale O by alpha (valid since arow_s synced above)
#pragma unroll
        for (int i = 0; i < 4; ++i) {
            float al = arow_s[(tm << 2) + i];
#pragma unroll
            for (int j = 0; j < 4; ++j) oacc[i][j] *= al;
        }

        // O += P @ V
#pragma unroll
        for (int t0 = 0; t0 < 64; t0 += 4) {
            float pr[4][4];
#pragma unroll
            for (int i = 0; i < 4; ++i) {
                float4 t = *(const float4*)&Ss[(tm << 2) + i][t0];
                pr[i][0] = t.x; pr[i][1] = t.y; pr[i][2] = t.z; pr[i][3] = t.w;
            }
#pragma unroll
            for (int tt = 0; tt < 4; ++tt) {
                float4 vv = *(const float4*)&Vs[t0 + tt][tn << 2];
#pragma unroll
                for (int i = 0; i < 4; ++i) {
                    oacc[i][0] += pr[i][tt] * vv.x;
                    oacc[i][1] += pr[i][tt] * vv.y;
                    oacc[i][2] += pr[i][tt] * vv.z;
                    oacc[i][3] += pr[i][tt] * vv.w;
                }
            }
        }
    }
    __syncthreads();   // lrow final

    // write [B, S, H*64]
    float* ob = o + ((size_t)b * SEQ + qt * 64) * DM + h * HD;
#pragma unroll
    for (int i = 0; i < 4; ++i) {
        int r = (tm << 2) + i;
        float invl = 1.0f / lrow[r];
        *(float4*)&ob[(size_t)r * DM + (tn << 2)] =
            make_float4(oacc[i][0] * invl, oacc[i][1] * invl,
                        oacc[i][2] * invl, oacc[i][3] * invl);
    }
}

// ---------------------------------------------------------------------------
// Kernel 3: out = attn @ Wo + bo   (8192x512 @ 512x512)
// ---------------------------------------------------------------------------
__global__ __launch_bounds__(256)
void out_gemm(const float* __restrict__ A, const float* __restrict__ W,
              const float* __restrict__ bias, float* __restrict__ out)
{
    __shared__ float As[16][68];
    __shared__ float Bs[16][68];
    const int tid  = threadIdx.x;
    const int tm   = tid >> 4, tn = tid & 15;
    const int row0 = blockIdx.x * 64;
    const int col0 = blockIdx.y * 64;

    const int arow = tid >> 2, ak4 = (tid & 3) << 2;
    const int brow = tid >> 4, bc4 = (tid & 15) << 2;

    float acc[4][4] = {};

    for (int k0 = 0; k0 < DM; k0 += 16) {
        float4 a = *(const float4*)&A[(size_t)(row0 + arow) * DM + k0 + ak4];
        As[ak4 + 0][arow] = a.x;
        As[ak4 + 1][arow] = a.y;
        As[ak4 + 2][arow] = a.z;
        As[ak4 + 3][arow] = a.w;
        *(float4*)&Bs[brow][bc4] =
            *(const float4*)&W[(size_t)(k0 + brow) * DM + col0 + bc4];
        __syncthreads();
#pragma unroll
        for (int kk = 0; kk < 16; ++kk) {
            float4 af = *(const float4*)&As[kk][tm << 2];
            float4 bf = *(const float4*)&Bs[kk][tn << 2];
            float av[4] = {af.x, af.y, af.z, af.w};
            float bv[4] = {bf.x, bf.y, bf.z, bf.w};
#pragma unroll
            for (int i = 0; i < 4; ++i)
#pragma unroll
                for (int j = 0; j < 4; ++j)
                    acc[i][j] += av[i] * bv[j];
        }
        __syncthreads();
    }

#pragma unroll
    for (int i = 0; i < 4; ++i) {
        int n = row0 + (tm << 2) + i;
        *(float4*)&out[(size_t)n * DM + col0 + (tn << 2)] =
            make_float4(acc[i][0] + bias[col0 + (tn << 2) + 0],
                        acc[i][1] + bias[col0 + (tn << 2) + 1],
                        acc[i][2] + bias[col0 + (tn << 2) + 2],
                        acc[i][3] + bias[col0 + (tn << 2) + 3]);
    }
}

// ---------------------------------------------------------------------------
extern "C" void kernel_launch(void* const* d_in, const int* in_sizes, int n_in,
                              void* d_out, int out_size, void* d_ws, size_t ws_size,
                              hipStream_t stream)
{
    const float* x    = (const float*)d_in[0];
    const float* Wqkv = (const float*)d_in[1];
    const float* bqkv = (const float*)d_in[2];
    const float* Wo   = (const float*)d_in[3];
    const float* bo   = (const float*)d_in[4];
    float* out = (float*)d_out;

    float* ws = (float*)d_ws;
    const size_t SZ = (size_t)4 * NH * SEQ * HD;   // 4,194,304 floats (16 MB)
    float* q    = ws;
    float* k    = ws + SZ;
    float* v    = ws + 2 * SZ;
    float* attn = ws + 3 * SZ;

    qkv_gemm_rope<<<dim3(128, 24), 256, 0, stream>>>(x, Wqkv, bqkv, q, k, v);
    attn_kernel<<<dim3(32, 32), 256, 0, stream>>>(q, k, v, attn);
    out_gemm<<<dim3(128, 8), 256, 0, stream>>>(attn, Wo, bo, out);
}

// Round 2
// 498.131 us; speedup vs baseline: 2.4739x; 2.4739x over previous
//
#include <hip/hip_runtime.h>
#include <math.h>

// Problem constants: B=4, S=2048, D=512, H=8, Hd=64
#define SEQ 2048
#define DM 512
#define NH 8
#define HD 64

typedef __bf16 bf16x8 __attribute__((ext_vector_type(8)));
typedef float f32x4 __attribute__((ext_vector_type(4)));
#define MFMA16(A, B, C) __builtin_amdgcn_mfma_f32_16x16x32_bf16(A, B, C, 0, 0, 0)

// ---------------------------------------------------------------------------
// Kernel 1: qkv = x @ Wqkv + bqkv, fused RoPE on q,k.
// q,k written [B,H,S,64]; v written TRANSPOSED [B,H,64,S] for MFMA B-frags.
// ---------------------------------------------------------------------------
__global__ __launch_bounds__(256)
void qkv_gemm_rope(const float* __restrict__ x, const float* __restrict__ W,
                   const float* __restrict__ bias,
                   float* __restrict__ qo, float* __restrict__ ko,
                   float* __restrict__ vo)
{
    __shared__ float As[16][68];   // [k][m], padded stride 68
    __shared__ float Bs[16][68];   // [k][n]
    const int tid  = threadIdx.x;
    const int tm   = tid >> 4, tn = tid & 15;
    const int row0 = blockIdx.x * 64;           // token tile
    const int bn   = blockIdx.y;                // 0..23
    const int col0 = bn * 64;

    const int arow = tid >> 2, ak4 = (tid & 3) << 2;
    const int brow = tid >> 4, bc4 = (tid & 15) << 2;

    float acc[4][4] = {};

    for (int k0 = 0; k0 < DM; k0 += 16) {
        float4 a = *(const float4*)&x[(size_t)(row0 + arow) * DM + k0 + ak4];
        As[ak4 + 0][arow] = a.x;
        As[ak4 + 1][arow] = a.y;
        As[ak4 + 2][arow] = a.z;
        As[ak4 + 3][arow] = a.w;
        *(float4*)&Bs[brow][bc4] =
            *(const float4*)&W[(size_t)(k0 + brow) * (3 * DM) + col0 + bc4];
        __syncthreads();
#pragma unroll
        for (int kk = 0; kk < 16; ++kk) {
            float4 af = *(const float4*)&As[kk][tm << 2];
            float4 bf = *(const float4*)&Bs[kk][tn << 2];
            float av[4] = {af.x, af.y, af.z, af.w};
            float bv[4] = {bf.x, bf.y, bf.z, bf.w};
#pragma unroll
            for (int i = 0; i < 4; ++i)
#pragma unroll
                for (int j = 0; j < 4; ++j)
                    acc[i][j] += av[i] * bv[j];
        }
        __syncthreads();
    }

    const int sel   = bn >> 3;      // 0=q 1=k 2=v
    const int head  = bn & 7;
    const int dbase = tn << 2;

    const float b0 = bias[col0 + dbase + 0];
    const float b1 = bias[col0 + dbase + 1];
    const float b2 = bias[col0 + dbase + 2];
    const float b3 = bias[col0 + dbase + 3];

    if (sel == 2) {
        // v: transposed write [B,H, d, s] — 4 float4 along s
        int n0 = row0 + (tm << 2);
        int b = n0 >> 11, s0 = n0 & (SEQ - 1);
        float bj[4] = {b0, b1, b2, b3};
#pragma unroll
        for (int j = 0; j < 4; ++j) {
            *(float4*)&vo[((size_t)(b * NH + head) * HD + dbase + j) * SEQ + s0] =
                make_float4(acc[0][j] + bj[j], acc[1][j] + bj[j],
                            acc[2][j] + bj[j], acc[3][j] + bj[j]);
        }
    } else {
        float* dst = (sel == 0) ? qo : ko;
        // inv_freq = exp(-d * ln(10000)/64), d even
        const float kln = -0.14391156660393256f;
        const float if0 = __expf(kln * (float)(dbase + 0));
        const float if1 = __expf(kln * (float)(dbase + 2));
#pragma unroll
        for (int i = 0; i < 4; ++i) {
            int n = row0 + (tm << 2) + i;
            int b = n >> 11, s = n & (SEQ - 1);
            float c0 = acc[i][0] + b0;
            float c1 = acc[i][1] + b1;
            float c2 = acc[i][2] + b2;
            float c3 = acc[i][3] + b3;
            float f0 = (float)s * if0;
            float f1 = (float)s * if1;
            float sn0, cs0, sn1, cs1;
            sincosf(f0, &sn0, &cs0);
            sincosf(f1, &sn1, &cs1);
            float r0 = c0 * cs0 - c1 * sn0;
            float r1 = c0 * sn0 + c1 * cs0;
            float r2 = c2 * cs1 - c3 * sn1;
            float r3 = c2 * sn1 + c3 * cs1;
            *(float4*)&dst[(((size_t)(b * NH + head) * SEQ + s) << 6) + dbase] =
                make_float4(r0, r1, r2, r3);
        }
    }
}

// ---------------------------------------------------------------------------
// Kernel 2: MFMA flash attention. Block = (b,h) x 64-row Q tile, 4 waves.
// Wave w owns Q rows w*16..+15. K split hi/lo (3-term QK^T), V single bf16.
// K/V staged in LDS pre-packed in MFMA B-frag order (conflict-free b128).
// P transposed C->A layout via per-wave LDS round trip.
// ---------------------------------------------------------------------------
__global__ __launch_bounds__(256, 3)
void attn_mfma(const float* __restrict__ q, const float* __restrict__ k,
               const float* __restrict__ vt, float* __restrict__ o)
{
    __shared__ __align__(16) __bf16 KH[4096];       // [kb][nt][lane][j]
    __shared__ __align__(16) __bf16 KL[4096];
    __shared__ __align__(16) __bf16 VF[4096];       // [tb][dt][lane][j]
    __shared__ __align__(16) __bf16 PW[4][16 * 72]; // per-wave P, stride 72

    const int tid  = threadIdx.x;
    const int lane = tid & 63;
    const int wave = tid >> 6;
    const int m    = lane & 15;
    const int quad = lane >> 4;

    const int bh = blockIdx.y;      // 0..31
    const int qt = blockIdx.x;      // 0..31
    const int bi = bh >> 3, h = bh & 7;

    const float* qp = q  + ((size_t)bh * SEQ + qt * 64 + wave * 16) * HD;
    const float* kp = k  + (size_t)bh * SEQ * HD;
    const float* vp = vt + (size_t)bh * HD * SEQ;

    // Q fragments (pre-scaled by 1/8), split hi/lo. A[m][k=c*32+quad*8+j]
    bf16x8 qhi[2], qlo[2];
#pragma unroll
    for (int c = 0; c < 2; ++c) {
        const float* qr = qp + (size_t)m * HD + c * 32 + quad * 8;
        float4 f0 = *(const float4*)qr;
        float4 f1 = *(const float4*)(qr + 4);
        float fv[8] = {f0.x, f0.y, f0.z, f0.w, f1.x, f1.y, f1.z, f1.w};
#pragma unroll
        for (int j = 0; j < 8; ++j) {
            float s = fv[j] * 0.125f;
            __bf16 hi = (__bf16)s;
            qhi[c][j] = hi;
            qlo[c][j] = (__bf16)(s - (float)hi);
        }
    }

    f32x4 oacc[4];
#pragma unroll
    for (int d = 0; d < 4; ++d) oacc[d] = (f32x4){0.f, 0.f, 0.f, 0.f};
    float mrow[4] = {-1e30f, -1e30f, -1e30f, -1e30f};
    float lrow[4] = {0.f, 0.f, 0.f, 0.f};

    for (int kt = 0; kt < SEQ / 64; ++kt) {
        __syncthreads();   // prior iteration's frag reads complete
        // ---- stage K (hi+lo) and V into frag-packed LDS ----
#pragma unroll
        for (int i = 0; i < 2; ++i) {
            int slot = i * 256 + tid;
            int r = slot >> 3, g = slot & 7;   // r: K row / VT row; g: 8-col group
            int fr = ((g >> 2) * 4 + (r >> 4)) * 64 + (r & 15) + 16 * (g & 3);
            {   // K[key=kt*64+r][dim=g*8..+7]
                const float* src = kp + (size_t)(kt * 64 + r) * HD + g * 8;
                float4 a0 = *(const float4*)src;
                float4 a1 = *(const float4*)(src + 4);
                float fv[8] = {a0.x, a0.y, a0.z, a0.w, a1.x, a1.y, a1.z, a1.w};
                bf16x8 hv, lv;
#pragma unroll
                for (int j = 0; j < 8; ++j) {
                    __bf16 hi = (__bf16)fv[j];
                    hv[j] = hi;
                    lv[j] = (__bf16)(fv[j] - (float)hi);
                }
                *(bf16x8*)&KH[fr * 8] = hv;
                *(bf16x8*)&KL[fr * 8] = lv;
            }
            {   // VT[d=r][t=kt*64+g*8..+7]
                const float* src = vp + (size_t)r * SEQ + kt * 64 + g * 8;
                float4 a0 = *(const float4*)src;
                float4 a1 = *(const float4*)(src + 4);
                float fv[8] = {a0.x, a0.y, a0.z, a0.w, a1.x, a1.y, a1.z, a1.w};
                bf16x8 hv;
#pragma unroll
                for (int j = 0; j < 8; ++j) hv[j] = (__bf16)fv[j];
                *(bf16x8*)&VF[fr * 8] = hv;
            }
        }
        __syncthreads();

        // ---- S = (Q/8) K^T : 16x64, 3-term split ----
        f32x4 sv[4];
#pragma unroll
        for (int nt = 0; nt < 4; ++nt) {
            f32x4 s = (f32x4){0.f, 0.f, 0.f, 0.f};
#pragma unroll
            for (int c = 0; c < 2; ++c) {
                bf16x8 bhv = *(const bf16x8*)&KH[((c * 4 + nt) * 64 + lane) * 8];
                bf16x8 blv = *(const bf16x8*)&KL[((c * 4 + nt) * 64 + lane) * 8];
                s = MFMA16(qhi[c], bhv, s);
                s = MFMA16(qlo[c], bhv, s);
                s = MFMA16(qhi[c], blv, s);
            }
            sv[nt] = s;   // S[row=quad*4+rg][key=nt*16+m]
        }

        // ---- online softmax (registers + shfl within 16-lane quad group) ----
        float tmax[4], alpha[4];
#pragma unroll
        for (int rg = 0; rg < 4; ++rg)
            tmax[rg] = fmaxf(fmaxf(sv[0][rg], sv[1][rg]),
                             fmaxf(sv[2][rg], sv[3][rg]));
#pragma unroll
        for (int off = 1; off < 16; off <<= 1)
#pragma unroll
            for (int rg = 0; rg < 4; ++rg)
                tmax[rg] = fmaxf(tmax[rg], __shfl_xor(tmax[rg], off));
#pragma unroll
        for (int rg = 0; rg < 4; ++rg) {
            float mn = fmaxf(mrow[rg], tmax[rg]);
            alpha[rg] = __expf(mrow[rg] - mn);
            mrow[rg] = mn;
        }
        float rs[4] = {0.f, 0.f, 0.f, 0.f};
        float pr[4][4];
#pragma unroll
        for (int nt = 0; nt < 4; ++nt)
#pragma unroll
            for (int rg = 0; rg < 4; ++rg) {
                float p = __expf(sv[nt][rg] - mrow[rg]);
                pr[nt][rg] = p;
                rs[rg] += p;
            }
#pragma unroll
        for (int off = 1; off < 16; off <<= 1)
#pragma unroll
            for (int rg = 0; rg < 4; ++rg)
                rs[rg] += __shfl_xor(rs[rg], off);
#pragma unroll
        for (int rg = 0; rg < 4; ++rg)
            lrow[rg] = lrow[rg] * alpha[rg] + rs[rg];
#pragma unroll
        for (int d = 0; d < 4; ++d)
#pragma unroll
            for (int rg = 0; rg < 4; ++rg)
                oacc[d][rg] *= alpha[rg];

        // ---- P: C-layout -> A-frag via per-wave LDS ----
        __bf16* pw = PW[wave];
#pragma unroll
        for (int nt = 0; nt < 4; ++nt)
#pragma unroll
            for (int rg = 0; rg < 4; ++rg)
                pw[(quad * 4 + rg) * 72 + nt * 16 + m] = (__bf16)pr[nt][rg];
        asm volatile("s_waitcnt lgkmcnt(0)" ::: "memory");
        bf16x8 pf0 = *(const bf16x8*)&pw[m * 72 + quad * 8];
        bf16x8 pf1 = *(const bf16x8*)&pw[m * 72 + 32 + quad * 8];

        // ---- O += P @ V ----
#pragma unroll
        for (int d = 0; d < 4; ++d) {
            bf16x8 v0 = *(const bf16x8*)&VF[((0 * 4 + d) * 64 + lane) * 8];
            bf16x8 v1 = *(const bf16x8*)&VF[((1 * 4 + d) * 64 + lane) * 8];
            oacc[d] = MFMA16(pf0, v0, oacc[d]);
            oacc[d] = MFMA16(pf1, v1, oacc[d]);
        }
    }

    // epilogue: write [B, S, H*64]
    float* ob = o + ((size_t)(bi * SEQ + qt * 64 + wave * 16 + quad * 4)) * DM
                  + h * HD + m;
#pragma unroll
    for (int rg = 0; rg < 4; ++rg) {
        float invl = 1.0f / lrow[rg];
#pragma unroll
        for (int d = 0; d < 4; ++d)
            ob[(size_t)rg * DM + d * 16] = oacc[d][rg] * invl;
    }
}

// ---------------------------------------------------------------------------
// Kernel 3: out = attn @ Wo + bo   (8192x512 @ 512x512)
// ---------------------------------------------------------------------------
__global__ __launch_bounds__(256)
void out_gemm(const float* __restrict__ A, const float* __restrict__ W,
              const float* __restrict__ bias, float* __restrict__ out)
{
    __shared__ float As[16][68];
    __shared__ float Bs[16][68];
    const int tid  = threadIdx.x;
    const int tm   = tid >> 4, tn = tid & 15;
    const int row0 = blockIdx.x * 64;
    const int col0 = blockIdx.y * 64;

    const int arow = tid >> 2, ak4 = (tid & 3) << 2;
    const int brow = tid >> 4, bc4 = (tid & 15) << 2;

    float acc[4][4] = {};

    for (int k0 = 0; k0 < DM; k0 += 16) {
        float4 a = *(const float4*)&A[(size_t)(row0 + arow) * DM + k0 + ak4];
        As[ak4 + 0][arow] = a.x;
        As[ak4 + 1][arow] = a.y;
        As[ak4 + 2][arow] = a.z;
        As[ak4 + 3][arow] = a.w;
        *(float4*)&Bs[brow][bc4] =
            *(const float4*)&W[(size_t)(k0 + brow) * DM + col0 + bc4];
        __syncthreads();
#pragma unroll
        for (int kk = 0; kk < 16; ++kk) {
            float4 af = *(const float4*)&As[kk][tm << 2];
            float4 bf = *(const float4*)&Bs[kk][tn << 2];
            float av[4] = {af.x, af.y, af.z, af.w};
            float bv[4] = {bf.x, bf.y, bf.z, bf.w};
#pragma unroll
            for (int i = 0; i < 4; ++i)
#pragma unroll
                for (int j = 0; j < 4; ++j)
                    acc[i][j] += av[i] * bv[j];
        }
        __syncthreads();
    }

#pragma unroll
    for (int i = 0; i < 4; ++i) {
        int n = row0 + (tm << 2) + i;
        *(float4*)&out[(size_t)n * DM + col0 + (tn << 2)] =
            make_float4(acc[i][0] + bias[col0 + (tn << 2) + 0],
                        acc[i][1] + bias[col0 + (tn << 2) + 1],
                        acc[i][2] + bias[col0 + (tn << 2) + 2],
                        acc[i][3] + bias[col0 + (tn << 2) + 3]);
    }
}

// ---------------------------------------------------------------------------
extern "C" void kernel_launch(void* const* d_in, const int* in_sizes, int n_in,
                              void* d_out, int out_size, void* d_ws, size_t ws_size,
                              hipStream_t stream)
{
    const float* x    = (const float*)d_in[0];
    const float* Wqkv = (const float*)d_in[1];
    const float* bqkv = (const float*)d_in[2];
    const float* Wo   = (const float*)d_in[3];
    const float* bo   = (const float*)d_in[4];
    float* out = (float*)d_out;

    float* ws = (float*)d_ws;
    const size_t SZ = (size_t)4 * NH * SEQ * HD;   // 4,194,304 floats
    float* q    = ws;            // [B,H,S,64]
    float* k    = ws + SZ;       // [B,H,S,64]
    float* vT   = ws + 2 * SZ;   // [B,H,64,S]
    float* attn = ws + 3 * SZ;   // [B,S,512]

    qkv_gemm_rope<<<dim3(128, 24), 256, 0, stream>>>(x, Wqkv, bqkv, q, k, vT);
    attn_mfma<<<dim3(32, 32), 256, 0, stream>>>(q, k, vT, attn);
    out_gemm<<<dim3(128, 8), 256, 0, stream>>>(attn, Wo, bo, out);
}

// Round 3
// 331.368 us; speedup vs baseline: 3.7189x; 1.5033x over previous
//
#include <hip/hip_runtime.h>
#include <math.h>

// Problem constants: B=4, S=2048, D=512, H=8, Hd=64
#define SEQ 2048
#define DM 512
#define NH 8
#define HD 64

typedef __bf16 bf16x8 __attribute__((ext_vector_type(8)));
typedef __bf16 bf16x4 __attribute__((ext_vector_type(4)));
typedef float f32x4 __attribute__((ext_vector_type(4)));
#define MFMA16(A, B, C) __builtin_amdgcn_mfma_f32_16x16x32_bf16(A, B, C, 0, 0, 0)

// ---------------------------------------------------------------------------
// Prep 1: RoPE table  tab[s][p] = (cos, sin)(s * 10000^(-p/32)), 2048x32
// ---------------------------------------------------------------------------
__global__ __launch_bounds__(256)
void prep_rope(float2* __restrict__ tab)
{
    int idx = blockIdx.x * 256 + threadIdx.x;   // 65536
    int s = idx >> 5, p = idx & 31;
    const float c = -0.28782313662425572f;      // -ln(10000)/32
    float f = (float)s * expf(c * (float)p);
    float sn, cs;
    sincosf(f, &sn, &cs);
    tab[idx] = make_float2(cs, sn);
}

// ---------------------------------------------------------------------------
// Prep 2: W [512][N] fp32  ->  Wt hi/lo bf16 [N][512] (transposed + split)
// ---------------------------------------------------------------------------
__global__ __launch_bounds__(256)
void prep_tw(const float* __restrict__ W, __bf16* __restrict__ hi,
             __bf16* __restrict__ lo, int N)
{
    int c = blockIdx.x * 256 + threadIdx.x;
    int k = blockIdx.y;
    float w = W[(size_t)k * N + c];
    __bf16 h = (__bf16)w;
    hi[(size_t)c * DM + k] = h;
    lo[(size_t)c * DM + k] = (__bf16)(w - (float)h);
}

// ---------------------------------------------------------------------------
// Kernel 1: QKV GEMM via split-bf16 MFMA (128x128 tile, 4 waves 2x2).
// Epilogue: bias + RoPE (table) ; writes q fp32 [B,H,S,64], khi/klo bf16
// [B,H,S,64], v bf16 transposed [B,H,64,S].
// ---------------------------------------------------------------------------
__global__ __launch_bounds__(256)
void qkv_mfma(const float* __restrict__ x, const __bf16* __restrict__ wth,
              const __bf16* __restrict__ wtl, const float* __restrict__ bias,
              const float2* __restrict__ tab,
              float* __restrict__ qo, __bf16* __restrict__ kho,
              __bf16* __restrict__ klo_, __bf16* __restrict__ vo)
{
    __shared__ __align__(16) __bf16 Ah[4096], Al[4096], Bh[4096], Bl[4096];

    const int tid  = threadIdx.x;
    const int lane = tid & 63;
    const int wave = tid >> 6;
    const int quad = lane >> 4;
    const int m    = lane & 15;
    const int wr   = wave >> 1, wc = wave & 1;
    const int row0 = blockIdx.x * 128;
    const int by   = blockIdx.y;            // 0..11
    const int col0 = by * 128;

    f32x4 acc[4][4];
#pragma unroll
    for (int i = 0; i < 4; ++i)
#pragma unroll
        for (int j = 0; j < 4; ++j) acc[i][j] = (f32x4){0.f, 0.f, 0.f, 0.f};

    for (int k0 = 0; k0 < DM; k0 += 32) {
#pragma unroll
        for (int i = 0; i < 2; ++i) {
            int u = i * 256 + tid;
            int r = (u & 15) + ((u >> 6) << 4);       // 0..127
            int g = (u >> 4) & 3;                     // k-octet
            int fa = ((r >> 4) << 6) + (g << 4) + (r & 15);
            // A: x fp32 -> hi/lo
            const float* ap = &x[(size_t)(row0 + r) * DM + k0 + (g << 3)];
            float4 a0 = *(const float4*)ap, a1 = *(const float4*)(ap + 4);
            float fv[8] = {a0.x, a0.y, a0.z, a0.w, a1.x, a1.y, a1.z, a1.w};
            bf16x8 hv, lv;
#pragma unroll
            for (int j = 0; j < 8; ++j) {
                __bf16 h = (__bf16)fv[j];
                hv[j] = h;
                lv[j] = (__bf16)(fv[j] - (float)h);
            }
            *(bf16x8*)&Ah[fa << 3] = hv;
            *(bf16x8*)&Al[fa << 3] = lv;
            // B: pre-split transposed W, pure copy (same index algebra)
            size_t boff = (size_t)(col0 + r) * DM + k0 + (g << 3);
            *(bf16x8*)&Bh[fa << 3] = *(const bf16x8*)&wth[boff];
            *(bf16x8*)&Bl[fa << 3] = *(const bf16x8*)&wtl[boff];
        }
        __syncthreads();

        bf16x8 avh[4], avl[4], bvh[4], bvl[4];
#pragma unroll
        for (int t = 0; t < 4; ++t) {
            int ai = ((((wr << 2) + t) << 6) + lane) << 3;
            int bi2 = ((((wc << 2) + t) << 6) + lane) << 3;
            avh[t] = *(const bf16x8*)&Ah[ai];
            avl[t] = *(const bf16x8*)&Al[ai];
            bvh[t] = *(const bf16x8*)&Bh[bi2];
            bvl[t] = *(const bf16x8*)&Bl[bi2];
        }
#pragma unroll
        for (int rt = 0; rt < 4; ++rt)
#pragma unroll
            for (int ct = 0; ct < 4; ++ct) {
                acc[rt][ct] = MFMA16(avh[rt], bvl[ct], acc[rt][ct]);
                acc[rt][ct] = MFMA16(avl[rt], bvh[ct], acc[rt][ct]);
                acc[rt][ct] = MFMA16(avh[rt], bvh[ct], acc[rt][ct]);
            }
        __syncthreads();
    }

    // ---- epilogue ----
    const int sel   = by >> 2;                  // 0=q 1=k 2=v
    const int head  = ((by << 1) + wc) & 7;
    const int row0w = row0 + wr * 64;
    const int bidx  = row0w >> 11;
    const int s0    = row0w & (SEQ - 1);
    const int colw  = col0 + wc * 64;

    if (sel == 2) {
#pragma unroll
        for (int ct = 0; ct < 4; ++ct) {
            int d = (ct << 4) + m;
            float bc = bias[colw + d];
#pragma unroll
            for (int rt = 0; rt < 4; ++rt) {
                f32x4 a = acc[rt][ct];
                bf16x4 ov;
#pragma unroll
                for (int rg = 0; rg < 4; ++rg) ov[rg] = (__bf16)(a[rg] + bc);
                size_t off = ((size_t)((bidx * NH + head) * HD + d)) * SEQ
                           + s0 + (rt << 4) + (quad << 2);
                *(bf16x4*)&vo[off] = ov;
            }
        }
    } else {
#pragma unroll
        for (int ct = 0; ct < 4; ++ct) {
            int d = (ct << 4) + m;
            float bc = bias[colw + d];
            int pairp = d >> 1;
            float sg = (m & 1) ? 1.0f : -1.0f;
#pragma unroll
            for (int rt = 0; rt < 4; ++rt) {
#pragma unroll
                for (int rg = 0; rg < 4; ++rg) {
                    float v = acc[rt][ct][rg] + bc;
                    float p = __shfl_xor(v, 1);
                    int s = s0 + (rt << 4) + (quad << 2) + rg;
                    float2 cs = tab[(s << 5) + pairp];
                    float r = v * cs.x + sg * p * cs.y;
                    size_t off = (((size_t)(bidx * NH + head) * SEQ + s) << 6) + d;
                    if (sel == 0) {
                        qo[off] = r;
                    } else {
                        __bf16 h = (__bf16)r;
                        kho[off]  = h;
                        klo_[off] = (__bf16)(r - (float)h);
                    }
                }
            }
        }
    }
}

// ---------------------------------------------------------------------------
// Kernel 2: MFMA flash attention (as R2, but K/V arrive pre-split bf16 ->
// staging is pure copies with a conflict-light slot mapping).
// ---------------------------------------------------------------------------
__global__ __launch_bounds__(256, 3)
void attn_mfma(const float* __restrict__ q, const __bf16* __restrict__ khi,
               const __bf16* __restrict__ klo, const __bf16* __restrict__ vt,
               float* __restrict__ o)
{
    __shared__ __align__(16) __bf16 KH[4096];
    __shared__ __align__(16) __bf16 KL[4096];
    __shared__ __align__(16) __bf16 VF[4096];
    __shared__ __align__(16) __bf16 PW[4][16 * 72];

    const int tid  = threadIdx.x;
    const int lane = tid & 63;
    const int wave = tid >> 6;
    const int m    = lane & 15;
    const int quad = lane >> 4;

    const int bh = blockIdx.y;
    const int qt = blockIdx.x;
    const int bi = bh >> 3, h = bh & 7;

    const float*  qp  = q   + ((size_t)bh * SEQ + qt * 64 + wave * 16) * HD;
    const __bf16* khp = khi + (size_t)bh * SEQ * HD;
    const __bf16* klp = klo + (size_t)bh * SEQ * HD;
    const __bf16* vp  = vt  + (size_t)bh * HD * SEQ;

    // Q fragments (pre-scaled by 1/8), split hi/lo. A[m][k=c*32+quad*8+j]
    bf16x8 qhi[2], qlo[2];
#pragma unroll
    for (int c = 0; c < 2; ++c) {
        const float* qr = qp + (size_t)m * HD + c * 32 + quad * 8;
        float4 f0 = *(const float4*)qr;
        float4 f1 = *(const float4*)(qr + 4);
        float fv[8] = {f0.x, f0.y, f0.z, f0.w, f1.x, f1.y, f1.z, f1.w};
#pragma unroll
        for (int j = 0; j < 8; ++j) {
            float s = fv[j] * 0.125f;
            __bf16 hi = (__bf16)s;
            qhi[c][j] = hi;
            qlo[c][j] = (__bf16)(s - (float)hi);
        }
    }

    f32x4 oacc[4];
#pragma unroll
    for (int d = 0; d < 4; ++d) oacc[d] = (f32x4){0.f, 0.f, 0.f, 0.f};
    float mrow[4] = {-1e30f, -1e30f, -1e30f, -1e30f};
    float lrow[4] = {0.f, 0.f, 0.f, 0.f};

    const int gst   = (tid >> 3) & 7;                       // dim-octet
    const int rbase = (tid & 7) + ((tid >> 6) << 3);        // row base

    for (int kt = 0; kt < SEQ / 64; ++kt) {
        __syncthreads();
#pragma unroll
        for (int i = 0; i < 2; ++i) {
            int r  = rbase + (i << 5);
            int fr = (((gst >> 2) << 2) + (r >> 4)) * 64 + ((gst & 3) << 4) + (r & 15);
            *(bf16x8*)&KH[fr << 3] =
                *(const bf16x8*)&khp[((size_t)(kt * 64 + r) << 6) + (gst << 3)];
            *(bf16x8*)&KL[fr << 3] =
                *(const bf16x8*)&klp[((size_t)(kt * 64 + r) << 6) + (gst << 3)];
            *(bf16x8*)&VF[fr << 3] =
                *(const bf16x8*)&vp[((size_t)r << 11) + kt * 64 + (gst << 3)];
        }
        __syncthreads();

        // ---- S = (Q/8) K^T : 16x64, 3-term split ----
        f32x4 sv[4];
#pragma unroll
        for (int nt = 0; nt < 4; ++nt) {
            f32x4 s = (f32x4){0.f, 0.f, 0.f, 0.f};
#pragma unroll
            for (int c = 0; c < 2; ++c) {
                bf16x8 bhv = *(const bf16x8*)&KH[((c * 4 + nt) * 64 + lane) << 3];
                bf16x8 blv = *(const bf16x8*)&KL[((c * 4 + nt) * 64 + lane) << 3];
                s = MFMA16(qhi[c], bhv, s);
                s = MFMA16(qlo[c], bhv, s);
                s = MFMA16(qhi[c], blv, s);
            }
            sv[nt] = s;
        }

        // ---- online softmax ----
        float tmax[4], alpha[4];
#pragma unroll
        for (int rg = 0; rg < 4; ++rg)
            tmax[rg] = fmaxf(fmaxf(sv[0][rg], sv[1][rg]),
                             fmaxf(sv[2][rg], sv[3][rg]));
#pragma unroll
        for (int off = 1; off < 16; off <<= 1)
#pragma unroll
            for (int rg = 0; rg < 4; ++rg)
                tmax[rg] = fmaxf(tmax[rg], __shfl_xor(tmax[rg], off));
#pragma unroll
        for (int rg = 0; rg < 4; ++rg) {
            float mn = fmaxf(mrow[rg], tmax[rg]);
            alpha[rg] = __expf(mrow[rg] - mn);
            mrow[rg] = mn;
        }
        float rs[4] = {0.f, 0.f, 0.f, 0.f};
        float pr[4][4];
#pragma unroll
        for (int nt = 0; nt < 4; ++nt)
#pragma unroll
            for (int rg = 0; rg < 4; ++rg) {
                float p = __expf(sv[nt][rg] - mrow[rg]);
                pr[nt][rg] = p;
                rs[rg] += p;
            }
#pragma unroll
        for (int off = 1; off < 16; off <<= 1)
#pragma unroll
            for (int rg = 0; rg < 4; ++rg)
                rs[rg] += __shfl_xor(rs[rg], off);
#pragma unroll
        for (int rg = 0; rg < 4; ++rg)
            lrow[rg] = lrow[rg] * alpha[rg] + rs[rg];
#pragma unroll
        for (int d = 0; d < 4; ++d)
#pragma unroll
            for (int rg = 0; rg < 4; ++rg)
                oacc[d][rg] *= alpha[rg];

        // ---- P: C-layout -> A-frag via per-wave LDS ----
        __bf16* pw = PW[wave];
#pragma unroll
        for (int nt = 0; nt < 4; ++nt)
#pragma unroll
            for (int rg = 0; rg < 4; ++rg)
                pw[(quad * 4 + rg) * 72 + nt * 16 + m] = (__bf16)pr[nt][rg];
        asm volatile("s_waitcnt lgkmcnt(0)" ::: "memory");
        bf16x8 pf0 = *(const bf16x8*)&pw[m * 72 + quad * 8];
        bf16x8 pf1 = *(const bf16x8*)&pw[m * 72 + 32 + quad * 8];

        // ---- O += P @ V ----
#pragma unroll
        for (int d = 0; d < 4; ++d) {
            bf16x8 v0 = *(const bf16x8*)&VF[((0 * 4 + d) * 64 + lane) << 3];
            bf16x8 v1 = *(const bf16x8*)&VF[((1 * 4 + d) * 64 + lane) << 3];
            oacc[d] = MFMA16(pf0, v0, oacc[d]);
            oacc[d] = MFMA16(pf1, v1, oacc[d]);
        }
    }

    // epilogue: write [B, S, H*64]
    float* ob = o + ((size_t)(bi * SEQ + qt * 64 + wave * 16 + quad * 4)) * DM
                  + h * HD + m;
#pragma unroll
    for (int rg = 0; rg < 4; ++rg) {
        float invl = 1.0f / lrow[rg];
#pragma unroll
        for (int d = 0; d < 4; ++d)
            ob[(size_t)rg * DM + d * 16] = oacc[d][rg] * invl;
    }
}

// ---------------------------------------------------------------------------
// Kernel 3: out = attn @ Wo + bo via split-bf16 MFMA (128x128 tile).
// ---------------------------------------------------------------------------
__global__ __launch_bounds__(256)
void out_mfma(const float* __restrict__ A, const __bf16* __restrict__ wth,
              const __bf16* __restrict__ wtl, const float* __restrict__ bias,
              float* __restrict__ out)
{
    __shared__ __align__(16) __bf16 Ah[4096], Al[4096], Bh[4096], Bl[4096];

    const int tid  = threadIdx.x;
    const int lane = tid & 63;
    const int wave = tid >> 6;
    const int quad = lane >> 4;
    const int m    = lane & 15;
    const int wr   = wave >> 1, wc = wave & 1;
    const int row0 = blockIdx.x * 128;
    const int col0 = blockIdx.y * 128;

    f32x4 acc[4][4];
#pragma unroll
    for (int i = 0; i < 4; ++i)
#pragma unroll
        for (int j = 0; j < 4; ++j) acc[i][j] = (f32x4){0.f, 0.f, 0.f, 0.f};

    for (int k0 = 0; k0 < DM; k0 += 32) {
#pragma unroll
        for (int i = 0; i < 2; ++i) {
            int u = i * 256 + tid;
            int r = (u & 15) + ((u >> 6) << 4);
            int g = (u >> 4) & 3;
            int fa = ((r >> 4) << 6) + (g << 4) + (r & 15);
            const float* ap = &A[(size_t)(row0 + r) * DM + k0 + (g << 3)];
            float4 a0 = *(const float4*)ap, a1 = *(const float4*)(ap + 4);
            float fv[8] = {a0.x, a0.y, a0.z, a0.w, a1.x, a1.y, a1.z, a1.w};
            bf16x8 hv, lv;
#pragma unroll
            for (int j = 0; j < 8; ++j) {
                __bf16 h = (__bf16)fv[j];
                hv[j] = h;
                lv[j] = (__bf16)(fv[j] - (float)h);
            }
            *(bf16x8*)&Ah[fa << 3] = hv;
            *(bf16x8*)&Al[fa << 3] = lv;
            size_t boff = (size_t)(col0 + r) * DM + k0 + (g << 3);
            *(bf16x8*)&Bh[fa << 3] = *(const bf16x8*)&wth[boff];
            *(bf16x8*)&Bl[fa << 3] = *(const bf16x8*)&wtl[boff];
        }
        __syncthreads();

        bf16x8 avh[4], avl[4], bvh[4], bvl[4];
#pragma unroll
        for (int t = 0; t < 4; ++t) {
            int ai  = ((((wr << 2) + t) << 6) + lane) << 3;
            int bi2 = ((((wc << 2) + t) << 6) + lane) << 3;
            avh[t] = *(const bf16x8*)&Ah[ai];
            avl[t] = *(const bf16x8*)&Al[ai];
            bvh[t] = *(const bf16x8*)&Bh[bi2];
            bvl[t] = *(const bf16x8*)&Bl[bi2];
        }
#pragma unroll
        for (int rt = 0; rt < 4; ++rt)
#pragma unroll
            for (int ct = 0; ct < 4; ++ct) {
                acc[rt][ct] = MFMA16(avh[rt], bvl[ct], acc[rt][ct]);
                acc[rt][ct] = MFMA16(avl[rt], bvh[ct], acc[rt][ct]);
                acc[rt][ct] = MFMA16(avh[rt], bvh[ct], acc[rt][ct]);
            }
        __syncthreads();
    }

    const int row0w = row0 + wr * 64;
    const int colw  = col0 + wc * 64;
#pragma unroll
    for (int ct = 0; ct < 4; ++ct) {
        int d = (ct << 4) + m;
        float bc = bias[colw + d];
#pragma unroll
        for (int rt = 0; rt < 4; ++rt)
#pragma unroll
            for (int rg = 0; rg < 4; ++rg) {
                int n = row0w + (rt << 4) + (quad << 2) + rg;
                out[(size_t)n * DM + colw + d] = acc[rt][ct][rg] + bc;
            }
    }
}

// ---------------------------------------------------------------------------
extern "C" void kernel_launch(void* const* d_in, const int* in_sizes, int n_in,
                              void* d_out, int out_size, void* d_ws, size_t ws_size,
                              hipStream_t stream)
{
    const float* x    = (const float*)d_in[0];
    const float* Wqkv = (const float*)d_in[1];
    const float* bqkv = (const float*)d_in[2];
    const float* Wo   = (const float*)d_in[3];
    const float* bo   = (const float*)d_in[4];
    float* out = (float*)d_out;

    char* ws = (char*)d_ws;
    const size_t MB = 1024 * 1024;
    float*  q     = (float*)(ws);                  // 16 MB [B,H,S,64] fp32
    float*  attn  = (float*)(ws + 16 * MB);        // 16 MB [B,S,512] fp32
    __bf16* khi   = (__bf16*)(ws + 32 * MB);       // 8 MB [B,H,S,64]
    __bf16* klo   = (__bf16*)(ws + 40 * MB);       // 8 MB
    __bf16* vT    = (__bf16*)(ws + 48 * MB);       // 8 MB [B,H,64,S]
    __bf16* wqt_h = (__bf16*)(ws + 56 * MB);       // 1.5 MB [1536][512]
    __bf16* wqt_l = (__bf16*)(ws + 56 * MB + 1536 * 1024);
    __bf16* wot_h = (__bf16*)(ws + 59 * MB);       // 0.5 MB [512][512]
    __bf16* wot_l = (__bf16*)(ws + 59 * MB + 512 * 1024);
    float2* rtab  = (float2*)(ws + 60 * MB);       // 0.5 MB [2048][32]

    prep_rope<<<256, 256, 0, stream>>>(rtab);
    prep_tw<<<dim3(6, 512), 256, 0, stream>>>(Wqkv, wqt_h, wqt_l, 3 * DM);
    prep_tw<<<dim3(2, 512), 256, 0, stream>>>(Wo, wot_h, wot_l, DM);
    qkv_mfma<<<dim3(64, 12), 256, 0, stream>>>(x, wqt_h, wqt_l, bqkv, rtab,
                                               q, khi, klo, vT);
    attn_mfma<<<dim3(32, 32), 256, 0, stream>>>(q, khi, klo, vT, attn);
    out_mfma<<<dim3(64, 4), 256, 0, stream>>>(attn, wot_h, wot_l, bo, out);
}

// Round 4
// 293.109 us; speedup vs baseline: 4.2043x; 1.1305x over previous
//
#include <hip/hip_runtime.h>
#include <math.h>

// Problem constants: B=4, S=2048, D=512, H=8, Hd=64
#define SEQ 2048
#define DM 512
#define NH 8
#define HD 64

typedef __bf16 bf16x8 __attribute__((ext_vector_type(8)));
typedef __bf16 bf16x4 __attribute__((ext_vector_type(4)));
typedef float f32x4 __attribute__((ext_vector_type(4)));
#define MFMA16(A, B, C) __builtin_amdgcn_mfma_f32_16x16x32_bf16(A, B, C, 0, 0, 0)

__device__ __forceinline__ void async16(const void* g, void* l) {
    __builtin_amdgcn_global_load_lds((__attribute__((address_space(1))) void*)g,
                                     (__attribute__((address_space(3))) void*)l,
                                     16, 0, 0);
}
#define LGKM0() asm volatile("s_waitcnt lgkmcnt(0)" ::: "memory")

// ---------------------------------------------------------------------------
// Prep 1: RoPE table  tab[s][p] = (cos, sin)(s * 10000^(-p/32)), 2048x32
// ---------------------------------------------------------------------------
__global__ __launch_bounds__(256)
void prep_rope(float2* __restrict__ tab)
{
    int idx = blockIdx.x * 256 + threadIdx.x;   // 65536
    int s = idx >> 5, p = idx & 31;
    const float c = -0.28782313662425572f;      // -ln(10000)/32
    float f = (float)s * expf(c * (float)p);
    float sn, cs;
    sincosf(f, &sn, &cs);
    tab[idx] = make_float2(cs, sn);
}

// ---------------------------------------------------------------------------
// Prep 2: W [512][N] fp32 -> Wt hi/lo bf16 [N][512] (transposed + split)
// ---------------------------------------------------------------------------
__global__ __launch_bounds__(256)
void prep_tw(const float* __restrict__ W, __bf16* __restrict__ hi,
             __bf16* __restrict__ lo, int N)
{
    int c = blockIdx.x * 256 + threadIdx.x;
    int k = blockIdx.y;
    float w = W[(size_t)k * N + c];
    __bf16 h = (__bf16)w;
    hi[(size_t)c * DM + k] = h;
    lo[(size_t)c * DM + k] = (__bf16)(w - (float)h);
}

// ---------------------------------------------------------------------------
// Prep 3: x fp32 -> xhi/xlo bf16 (row-major [8192][512])
// ---------------------------------------------------------------------------
__global__ __launch_bounds__(256)
void prep_x(const float* __restrict__ x, __bf16* __restrict__ xh,
            __bf16* __restrict__ xl)
{
    size_t i = ((size_t)blockIdx.x * 256 + threadIdx.x) << 3;
    float4 a0 = *(const float4*)&x[i];
    float4 a1 = *(const float4*)&x[i + 4];
    float fv[8] = {a0.x, a0.y, a0.z, a0.w, a1.x, a1.y, a1.z, a1.w};
    bf16x8 hv, lv;
#pragma unroll
    for (int j = 0; j < 8; ++j) {
        __bf16 h = (__bf16)fv[j];
        hv[j] = h;
        lv[j] = (__bf16)(fv[j] - (float)h);
    }
    *(bf16x8*)&xh[i] = hv;
    *(bf16x8*)&xl[i] = lv;
}

// ---------------------------------------------------------------------------
// Kernel 1: QKV GEMM, pure async-staged split-bf16 MFMA (128x128, 4 waves).
// Epilogue: LDS transpose -> bias + RoPE -> vector stores.
// q fp32 [B,H,S,64]; khi/klo bf16 [B,H,S,64]; v bf16 transposed [B,H,64,S].
// ---------------------------------------------------------------------------
__global__ __launch_bounds__(256)
void qkv_mfma(const __bf16* __restrict__ xh, const __bf16* __restrict__ xl,
              const __bf16* __restrict__ wth, const __bf16* __restrict__ wtl,
              const float* __restrict__ bias, const float2* __restrict__ tab,
              float* __restrict__ qo, __bf16* __restrict__ kho,
              __bf16* __restrict__ klo_, __bf16* __restrict__ vo)
{
    __shared__ __align__(16) __bf16 SM[16384];      // 32 KB
    __bf16* Ah = SM;
    __bf16* Al = SM + 4096;
    __bf16* Bh = SM + 8192;
    __bf16* Bl = SM + 12288;

    const int tid  = threadIdx.x;
    const int lane = tid & 63;
    const int wave = tid >> 6;
    const int quad = lane >> 4;
    const int m    = lane & 15;
    const int wr   = wave >> 1, wc = wave & 1;
    const int row0 = blockIdx.x * 128;
    const int by   = blockIdx.y;            // 0..11
    const int col0 = by * 128;

    // async-copy addressing: frag block rb holds rows rb*16+(lane&15), k-octet lane>>4
    const size_t aoff0 = (size_t)(row0 + wave * 16 + m) * DM + (quad << 3);
    const size_t aoff1 = (size_t)(row0 + (wave + 4) * 16 + m) * DM + (quad << 3);
    const size_t boff0 = (size_t)(col0 + wave * 16 + m) * DM + (quad << 3);
    const size_t boff1 = (size_t)(col0 + (wave + 4) * 16 + m) * DM + (quad << 3);
    __bf16* lA0 = &Ah[wave << 9];       __bf16* lA1 = &Ah[(wave + 4) << 9];
    __bf16* lAl0 = &Al[wave << 9];      __bf16* lAl1 = &Al[(wave + 4) << 9];
    __bf16* lB0 = &Bh[wave << 9];       __bf16* lB1 = &Bh[(wave + 4) << 9];
    __bf16* lBl0 = &Bl[wave << 9];      __bf16* lBl1 = &Bl[(wave + 4) << 9];

    f32x4 acc[4][4];
#pragma unroll
    for (int i = 0; i < 4; ++i)
#pragma unroll
        for (int j = 0; j < 4; ++j) acc[i][j] = (f32x4){0.f, 0.f, 0.f, 0.f};

    for (int k0 = 0; k0 < DM; k0 += 32) {
        async16(xh + aoff0 + k0, lA0);
        async16(xh + aoff1 + k0, lA1);
        async16(xl + aoff0 + k0, lAl0);
        async16(xl + aoff1 + k0, lAl1);
        async16(wth + boff0 + k0, lB0);
        async16(wth + boff1 + k0, lB1);
        async16(wtl + boff0 + k0, lBl0);
        async16(wtl + boff1 + k0, lBl1);
        __syncthreads();

        bf16x8 avh[4], avl[4], bvh[4], bvl[4];
#pragma unroll
        for (int t = 0; t < 4; ++t) {
            int ai  = ((((wr << 2) + t) << 6) + lane) << 3;
            int bi2 = ((((wc << 2) + t) << 6) + lane) << 3;
            avh[t] = *(const bf16x8*)&Ah[ai];
            avl[t] = *(const bf16x8*)&Al[ai];
            bvh[t] = *(const bf16x8*)&Bh[bi2];
            bvl[t] = *(const bf16x8*)&Bl[bi2];
        }
#pragma unroll
        for (int rt = 0; rt < 4; ++rt)
#pragma unroll
            for (int ct = 0; ct < 4; ++ct) {
                acc[rt][ct] = MFMA16(avh[rt], bvl[ct], acc[rt][ct]);
                acc[rt][ct] = MFMA16(avl[rt], bvh[ct], acc[rt][ct]);
                acc[rt][ct] = MFMA16(avh[rt], bvh[ct], acc[rt][ct]);
            }
        __syncthreads();
    }

    // ---- epilogue ----
    const int sel   = by >> 2;              // 0=q 1=k 2=v
    const int head  = ((by << 1) + wc) & 7;
    const int row0w = row0 + wr * 64;
    const int bidx  = row0w >> 11;
    const int s0    = row0w & (SEQ - 1);
    const int colw  = col0 + wc * 64;

    float bc[4];
#pragma unroll
    for (int ct = 0; ct < 4; ++ct) bc[ct] = bias[colw + (ct << 4) + m];

    if (sel == 2) {
        // v: direct transposed store [B,H,d,s], bf16x4 along s
#pragma unroll
        for (int ct = 0; ct < 4; ++ct) {
            int d = (ct << 4) + m;
#pragma unroll
            for (int rt = 0; rt < 4; ++rt) {
                f32x4 a = acc[rt][ct];
                bf16x4 ov;
#pragma unroll
                for (int rg = 0; rg < 4; ++rg) ov[rg] = (__bf16)(a[rg] + bc[ct]);
                size_t off = ((size_t)((bidx * NH + head) * HD + d)) * SEQ
                           + s0 + (rt << 4) + (quad << 2);
                *(bf16x4*)&vo[off] = ov;
            }
        }
    } else {
        // q/k: per-wave LDS transpose + RoPE + vector stores
        float* tb = (float*)SM + wave * 1088;       // 16 x 68 f32
        const int rr = lane >> 2, jj = lane & 3;
#pragma unroll
        for (int rt = 0; rt < 4; ++rt) {
#pragma unroll
            for (int ct = 0; ct < 4; ++ct)
#pragma unroll
                for (int rg = 0; rg < 4; ++rg)
                    tb[((quad << 2) + rg) * 68 + (ct << 4) + m] =
                        acc[rt][ct][rg] + bc[ct];
            LGKM0();
            int s = (row0w + (rt << 4) + rr) & (SEQ - 1);
#pragma unroll
            for (int i = 0; i < 4; ++i) {
                int c = (jj << 2) + (i << 4);
                float4 vv = *(const float4*)&tb[rr * 68 + c];
                float4 t4 = *(const float4*)&tab[(s << 5) + (c >> 1)];
                float r0 = vv.x * t4.x - vv.y * t4.y;
                float r1 = vv.x * t4.y + vv.y * t4.x;
                float r2 = vv.z * t4.z - vv.w * t4.w;
                float r3 = vv.z * t4.w + vv.w * t4.z;
                size_t off = (((size_t)(bidx * NH + head) * SEQ + s) << 6) + c;
                if (sel == 0) {
                    *(float4*)&qo[off] = make_float4(r0, r1, r2, r3);
                } else {
                    float rv[4] = {r0, r1, r2, r3};
                    bf16x4 hv, lv;
#pragma unroll
                    for (int j = 0; j < 4; ++j) {
                        __bf16 h = (__bf16)rv[j];
                        hv[j] = h;
                        lv[j] = (__bf16)(rv[j] - (float)h);
                    }
                    *(bf16x4*)&kho[off]  = hv;
                    *(bf16x4*)&klo_[off] = lv;
                }
            }
        }
    }
}

// ---------------------------------------------------------------------------
// Kernel 2: MFMA flash attention, S^T orientation.
// S^T = K·Q^T  (C-layout col = q-row -> per-lane softmax state, 2-shfl
// reductions, bf16x4 P stores). Async global->LDS staging for K/V.
// Output written pre-split hi/lo bf16 for the out GEMM.
// ---------------------------------------------------------------------------
__global__ __launch_bounds__(256, 3)
void attn_mfma(const float* __restrict__ q, const __bf16* __restrict__ khi,
               const __bf16* __restrict__ klo, const __bf16* __restrict__ vt,
               __bf16* __restrict__ oh, __bf16* __restrict__ ol)
{
    __shared__ __align__(16) __bf16 KH[4096];
    __shared__ __align__(16) __bf16 KL[4096];
    __shared__ __align__(16) __bf16 VF[4096];
    __shared__ __align__(16) __bf16 PW[4608];   // 4 waves x 16 x 72

    const int tid  = threadIdx.x;
    const int lane = tid & 63;
    const int wave = tid >> 6;
    const int m    = lane & 15;
    const int quad = lane >> 4;

    const int bh = blockIdx.y;
    const int qt = blockIdx.x;
    const int bi = bh >> 3, h = bh & 7;

    const float*  qp  = q   + ((size_t)bh * SEQ + qt * 64 + wave * 16) * HD;
    const __bf16* khp = khi + (size_t)bh * SEQ * HD;
    const __bf16* klp = klo + (size_t)bh * SEQ * HD;
    const __bf16* vp  = vt  + (size_t)bh * HD * SEQ;

    // Q fragments, scale = 0.125 * log2(e) folded in; split hi/lo.
    const float SCALE = 0.18033688011112042f;
    bf16x8 qhi[2], qlo[2];
#pragma unroll
    for (int c = 0; c < 2; ++c) {
        const float* qr = qp + (size_t)m * HD + c * 32 + quad * 8;
        float4 f0 = *(const float4*)qr;
        float4 f1 = *(const float4*)(qr + 4);
        float fv[8] = {f0.x, f0.y, f0.z, f0.w, f1.x, f1.y, f1.z, f1.w};
#pragma unroll
        for (int j = 0; j < 8; ++j) {
            float s = fv[j] * SCALE;
            __bf16 hi = (__bf16)s;
            qhi[c][j] = hi;
            qlo[c][j] = (__bf16)(s - (float)hi);
        }
    }

    // async staging addresses (frag block fb = c*4 + wave; lane slot = lane)
    const size_t koff0 = ((size_t)(wave * 16 + m) << 6) + (quad << 3);   // c=0
    const size_t koff1 = koff0 + 32;                                     // c=1
    const size_t voff0 = ((size_t)(wave * 16 + m) << 11) + (quad << 3);
    const size_t voff1 = voff0 + 32;
    __bf16* lkh0 = &KH[wave << 9];   __bf16* lkh1 = &KH[(wave + 4) << 9];
    __bf16* lkl0 = &KL[wave << 9];   __bf16* lkl1 = &KL[(wave + 4) << 9];
    __bf16* lvf0 = &VF[wave << 9];   __bf16* lvf1 = &VF[(wave + 4) << 9];

    f32x4 oacc[4];
#pragma unroll
    for (int d = 0; d < 4; ++d) oacc[d] = (f32x4){0.f, 0.f, 0.f, 0.f};
    float mrow = -1e30f, lrow = 0.f;

    for (int kt = 0; kt < SEQ / 64; ++kt) {
        __syncthreads();   // prior tile's readers done
        async16(khp + koff0 + ((size_t)kt << 12), lkh0);
        async16(khp + koff1 + ((size_t)kt << 12), lkh1);
        async16(klp + koff0 + ((size_t)kt << 12), lkl0);
        async16(klp + koff1 + ((size_t)kt << 12), lkl1);
        async16(vp + voff0 + ((size_t)kt << 6), lvf0);
        async16(vp + voff1 + ((size_t)kt << 6), lvf1);
        __syncthreads();   // copies landed

        // ---- S^T = K (hi/lo) · Q^T : 64 keys x 16 q ----
        f32x4 sv[4];
#pragma unroll
        for (int nt = 0; nt < 4; ++nt) {
            f32x4 s = (f32x4){0.f, 0.f, 0.f, 0.f};
#pragma unroll
            for (int c = 0; c < 2; ++c) {
                bf16x8 kh = *(const bf16x8*)&KH[((c * 4 + nt) * 64 + lane) << 3];
                bf16x8 kl = *(const bf16x8*)&KL[((c * 4 + nt) * 64 + lane) << 3];
                s = MFMA16(kh, qhi[c], s);
                s = MFMA16(kh, qlo[c], s);
                s = MFMA16(kl, qhi[c], s);
            }
            sv[nt] = s;   // S^T[key = nt*16+quad*4+rg][q = m], log2-domain
        }

        // ---- online softmax, per-lane (q = m), 2-shfl reductions ----
        float tm = sv[0][0];
#pragma unroll
        for (int nt = 0; nt < 4; ++nt)
#pragma unroll
            for (int rg = 0; rg < 4; ++rg) tm = fmaxf(tm, sv[nt][rg]);
        tm = fmaxf(tm, __shfl_xor(tm, 16));
        tm = fmaxf(tm, __shfl_xor(tm, 32));
        float mn = fmaxf(mrow, tm);
        float alpha = exp2f(mrow - mn);
        mrow = mn;
        float pr[4][4];
        float rs = 0.f;
#pragma unroll
        for (int nt = 0; nt < 4; ++nt)
#pragma unroll
            for (int rg = 0; rg < 4; ++rg) {
                float p = exp2f(sv[nt][rg] - mn);
                pr[nt][rg] = p;
                rs += p;
            }
        rs += __shfl_xor(rs, 16);
        rs += __shfl_xor(rs, 32);
        lrow = lrow * alpha + rs;
        float al[4];
#pragma unroll
        for (int rg = 0; rg < 4; ++rg)
            al[rg] = __shfl(alpha, (quad << 2) + rg, 16);
#pragma unroll
        for (int d = 0; d < 4; ++d)
#pragma unroll
            for (int rg = 0; rg < 4; ++rg) oacc[d][rg] *= al[rg];

        // ---- P^T (C-layout) -> A-frag staging: bf16x4 vector stores ----
        __bf16* pw = PW + wave * 1152;
#pragma unroll
        for (int nt = 0; nt < 4; ++nt) {
            bf16x4 p4;
#pragma unroll
            for (int rg = 0; rg < 4; ++rg) p4[rg] = (__bf16)pr[nt][rg];
            *(bf16x4*)&pw[m * 72 + (nt << 4) + (quad << 2)] = p4;
        }
        LGKM0();
        bf16x8 pf0 = *(const bf16x8*)&pw[m * 72 + (quad << 3)];
        bf16x8 pf1 = *(const bf16x8*)&pw[m * 72 + 32 + (quad << 3)];

        // ---- O += P @ V ----
#pragma unroll
        for (int d = 0; d < 4; ++d) {
            bf16x8 v0 = *(const bf16x8*)&VF[((0 * 4 + d) * 64 + lane) << 3];
            bf16x8 v1 = *(const bf16x8*)&VF[((1 * 4 + d) * 64 + lane) << 3];
            oacc[d] = MFMA16(pf0, v0, oacc[d]);
            oacc[d] = MFMA16(pf1, v1, oacc[d]);
        }
    }

    // epilogue: normalize, split hi/lo, write [B,S,512]
    float inv = 1.0f / lrow;
    float il[4];
#pragma unroll
    for (int rg = 0; rg < 4; ++rg)
        il[rg] = __shfl(inv, (quad << 2) + rg, 16);
    size_t ob = ((size_t)(bi * SEQ + qt * 64 + wave * 16 + (quad << 2))) * DM
              + h * HD + m;
#pragma unroll
    for (int rg = 0; rg < 4; ++rg)
#pragma unroll
        for (int d = 0; d < 4; ++d) {
            float val = oacc[d][rg] * il[rg];
            __bf16 hv = (__bf16)val;
            oh[ob + (size_t)rg * DM + d * 16] = hv;
            ol[ob + (size_t)rg * DM + d * 16] = (__bf16)(val - (float)hv);
        }
}

// ---------------------------------------------------------------------------
// Kernel 3: out = attn @ Wo + bo, async-staged split-bf16 MFMA (128x128).
// ---------------------------------------------------------------------------
__global__ __launch_bounds__(256)
void out_mfma(const __bf16* __restrict__ ah, const __bf16* __restrict__ al_,
              const __bf16* __restrict__ wth, const __bf16* __restrict__ wtl,
              const float* __restrict__ bias, float* __restrict__ out)
{
    __shared__ __align__(16) __bf16 SM[16384];
    __bf16* Ah = SM;
    __bf16* Al = SM + 4096;
    __bf16* Bh = SM + 8192;
    __bf16* Bl = SM + 12288;

    const int tid  = threadIdx.x;
    const int lane = tid & 63;
    const int wave = tid >> 6;
    const int quad = lane >> 4;
    const int m    = lane & 15;
    const int wr   = wave >> 1, wc = wave & 1;
    const int row0 = blockIdx.x * 128;
    const int col0 = blockIdx.y * 128;

    const size_t aoff0 = (size_t)(row0 + wave * 16 + m) * DM + (quad << 3);
    const size_t aoff1 = (size_t)(row0 + (wave + 4) * 16 + m) * DM + (quad << 3);
    const size_t boff0 = (size_t)(col0 + wave * 16 + m) * DM + (quad << 3);
    const size_t boff1 = (size_t)(col0 + (wave + 4) * 16 + m) * DM + (quad << 3);
    __bf16* lA0 = &Ah[wave << 9];       __bf16* lA1 = &Ah[(wave + 4) << 9];
    __bf16* lAl0 = &Al[wave << 9];      __bf16* lAl1 = &Al[(wave + 4) << 9];
    __bf16* lB0 = &Bh[wave << 9];       __bf16* lB1 = &Bh[(wave + 4) << 9];
    __bf16* lBl0 = &Bl[wave << 9];      __bf16* lBl1 = &Bl[(wave + 4) << 9];

    f32x4 acc[4][4];
#pragma unroll
    for (int i = 0; i < 4; ++i)
#pragma unroll
        for (int j = 0; j < 4; ++j) acc[i][j] = (f32x4){0.f, 0.f, 0.f, 0.f};

    for (int k0 = 0; k0 < DM; k0 += 32) {
        async16(ah + aoff0 + k0, lA0);
        async16(ah + aoff1 + k0, lA1);
        async16(al_ + aoff0 + k0, lAl0);
        async16(al_ + aoff1 + k0, lAl1);
        async16(wth + boff0 + k0, lB0);
        async16(wth + boff1 + k0, lB1);
        async16(wtl + boff0 + k0, lBl0);
        async16(wtl + boff1 + k0, lBl1);
        __syncthreads();

        bf16x8 avh[4], avl[4], bvh[4], bvl[4];
#pragma unroll
        for (int t = 0; t < 4; ++t) {
            int ai  = ((((wr << 2) + t) << 6) + lane) << 3;
            int bi2 = ((((wc << 2) + t) << 6) + lane) << 3;
            avh[t] = *(const bf16x8*)&Ah[ai];
            avl[t] = *(const bf16x8*)&Al[ai];
            bvh[t] = *(const bf16x8*)&Bh[bi2];
            bvl[t] = *(const bf16x8*)&Bl[bi2];
        }
#pragma unroll
        for (int rt = 0; rt < 4; ++rt)
#pragma unroll
            for (int ct = 0; ct < 4; ++ct) {
                acc[rt][ct] = MFMA16(avh[rt], bvl[ct], acc[rt][ct]);
                acc[rt][ct] = MFMA16(avl[rt], bvh[ct], acc[rt][ct]);
                acc[rt][ct] = MFMA16(avh[rt], bvh[ct], acc[rt][ct]);
            }
        __syncthreads();
    }

    // epilogue: LDS transpose -> coalesced float4 stores
    const int row0w = row0 + wr * 64;
    const int colw  = col0 + wc * 64;
    float bc[4];
#pragma unroll
    for (int ct = 0; ct < 4; ++ct) bc[ct] = bias[colw + (ct << 4) + m];

    float* tb = (float*)SM + wave * 1088;
    const int rr = lane >> 2, jj = lane & 3;
#pragma unroll
    for (int rt = 0; rt < 4; ++rt) {
#pragma unroll
        for (int ct = 0; ct < 4; ++ct)
#pragma unroll
            for (int rg = 0; rg < 4; ++rg)
                tb[((quad << 2) + rg) * 68 + (ct << 4) + m] =
                    acc[rt][ct][rg] + bc[ct];
        LGKM0();
        int n = row0w + (rt << 4) + rr;
#pragma unroll
        for (int i = 0; i < 4; ++i) {
            int c = (jj << 2) + (i << 4);
            *(float4*)&out[(size_t)n * DM + colw + c] =
                *(const float4*)&tb[rr * 68 + c];
        }
    }
}

// ---------------------------------------------------------------------------
extern "C" void kernel_launch(void* const* d_in, const int* in_sizes, int n_in,
                              void* d_out, int out_size, void* d_ws, size_t ws_size,
                              hipStream_t stream)
{
    const float* x    = (const float*)d_in[0];
    const float* Wqkv = (const float*)d_in[1];
    const float* bqkv = (const float*)d_in[2];
    const float* Wo   = (const float*)d_in[3];
    const float* bo   = (const float*)d_in[4];
    float* out = (float*)d_out;

    char* ws = (char*)d_ws;
    const size_t MB = 1024 * 1024;
    float*  q     = (float*)(ws);                          // 16 MB [B,H,S,64]
    __bf16* xhi   = (__bf16*)(ws + 16 * MB);               // 8 MB (later: ohi)
    __bf16* xlo   = (__bf16*)(ws + 24 * MB);               // 8 MB (later: olo)
    __bf16* khi   = (__bf16*)(ws + 32 * MB);               // 8 MB [B,H,S,64]
    __bf16* klo   = (__bf16*)(ws + 40 * MB);               // 8 MB
    __bf16* vT    = (__bf16*)(ws + 48 * MB);               // 8 MB [B,H,64,S]
    __bf16* wqt_h = (__bf16*)(ws + 56 * MB);               // 1.5 MB [1536][512]
    __bf16* wqt_l = (__bf16*)(ws + 56 * MB + 1536 * 1024);
    __bf16* wot_h = (__bf16*)(ws + 59 * MB);               // 0.5 MB [512][512]
    __bf16* wot_l = (__bf16*)(ws + 59 * MB + 512 * 1024);
    float2* rtab  = (float2*)(ws + 60 * MB);               // 0.5 MB [2048][32]

    prep_rope<<<256, 256, 0, stream>>>(rtab);
    prep_tw<<<dim3(6, 512), 256, 0, stream>>>(Wqkv, wqt_h, wqt_l, 3 * DM);
    prep_tw<<<dim3(2, 512), 256, 0, stream>>>(Wo, wot_h, wot_l, DM);
    prep_x<<<2048, 256, 0, stream>>>(x, xhi, xlo);
    qkv_mfma<<<dim3(64, 12), 256, 0, stream>>>(xhi, xlo, wqt_h, wqt_l, bqkv,
                                               rtab, q, khi, klo, vT);
    attn_mfma<<<dim3(32, 32), 256, 0, stream>>>(q, khi, klo, vT, xhi, xlo);
    out_mfma<<<dim3(64, 4), 256, 0, stream>>>(xhi, xlo, wot_h, wot_l, bo, out);
}